// Round 3
// baseline (261.629 us; speedup 1.0000x reference)
//
#include <hip/hip_runtime.h>
#include <hip/hip_bf16.h>
#include <cstdint>

// GatedMultiheadAttention: B=2, N=2048, E=1024, H=16, D=64
// R3: attn -> 128-thread blocks, 64 q-rows/wave (halves LDS frag traffic/row);
// QKV projections fused into one 768-block dispatch; V^T lives in d_out (dead
// until final GEMM). ws (48MB): W 0-8 | XQ 8-16, XK 16-24, XV 24-32,
// QB 32-40, KB 40-48 | AOB = 8-16 (over dead XQ). VTB = d_out.

#define DEV __device__ __forceinline__
typedef __attribute__((ext_vector_type(8))) short bf16x8;
typedef __attribute__((ext_vector_type(4))) float f32x4;
typedef unsigned short u16;

DEV void async16(const void* g, void* l) {
  __builtin_amdgcn_global_load_lds(
      (const __attribute__((address_space(1))) unsigned int*)g,
      (__attribute__((address_space(3))) unsigned int*)l, 16, 0, 0);
}

DEV u16 bf16_rne(float f) {
  unsigned int u = __builtin_bit_cast(unsigned int, f);
  u += 0x7FFFu + ((u >> 16) & 1u);
  return (u16)(u >> 16);
}

DEV u16 cvt16(float x) {  // single-instr path on gfx950 (v_cvt_pk_bf16_f32)
  __hip_bfloat16 h = __float2bfloat16(x);
  return __builtin_bit_cast(u16, h);
}

// ---------------- one fused cast: q,k,v + 4 weights ----------------
__global__ __launch_bounds__(256) void cast_all(
    const float* __restrict__ q, const float* __restrict__ k, const float* __restrict__ v,
    const float* __restrict__ Wq, const float* __restrict__ Wk,
    const float* __restrict__ Wv, const float* __restrict__ Wo,
    u16* __restrict__ XQ, u16* __restrict__ XK, u16* __restrict__ XV,
    u16* __restrict__ WQB, u16* __restrict__ WKB, u16* __restrict__ WVB,
    u16* __restrict__ WOB) {
  int idx = blockIdx.x * 256 + threadIdx.x;  // one 8-elem item each
  const float* src; u16* dst; int i;
  if      (idx <  524288) { src = q;  dst = XQ;  i = idx; }
  else if (idx < 1048576) { src = k;  dst = XK;  i = idx -  524288; }
  else if (idx < 1572864) { src = v;  dst = XV;  i = idx - 1048576; }
  else if (idx < 1703936) { src = Wq; dst = WQB; i = idx - 1572864; }
  else if (idx < 1835008) { src = Wk; dst = WKB; i = idx - 1703936; }
  else if (idx < 1966080) { src = Wv; dst = WVB; i = idx - 1835008; }
  else                    { src = Wo; dst = WOB; i = idx - 1966080; }
  const float4* p = (const float4*)src + (size_t)i * 2;
  float4 a = p[0], b = p[1];
  union { u16 us[8]; uint4 vv; } u;
  u.us[0] = bf16_rne(a.x); u.us[1] = bf16_rne(a.y);
  u.us[2] = bf16_rne(a.z); u.us[3] = bf16_rne(a.w);
  u.us[4] = bf16_rne(b.x); u.us[5] = bf16_rne(b.y);
  u.us[6] = bf16_rne(b.z); u.us[7] = bf16_rne(b.w);
  ((uint4*)dst)[i] = u.vv;
}

// ---------------- fused QKV projection GEMM (768 blocks, 128x128, dbuf) ------
// seg = bx>>8: 0=Q (gate-scale folded), 1=K, 2=V (writes V^T into d_out).
__global__ __launch_bounds__(256, 2) void gemm_qkv(
    const u16* __restrict__ XQ, const u16* __restrict__ XK, const u16* __restrict__ XV,
    const u16* __restrict__ Wb,  // WQ|WK|WV contiguous, 1M elems apart
    const float* __restrict__ bq, const float* __restrict__ bkb, const float* __restrict__ bv,
    const float* __restrict__ gate,
    u16* __restrict__ QB, u16* __restrict__ KB, u16* __restrict__ VTB) {
  __shared__ __attribute__((aligned(16))) u16 As[2][128 * 32];
  __shared__ __attribute__((aligned(16))) u16 Bs[2][128 * 32];
  const int t = threadIdx.x, lane = t & 63, w = t >> 6;
  const int l15 = lane & 15, quad = lane >> 4;
  const int seg = blockIdx.x >> 8, inner = blockIdx.x & 255;
  const int bm = inner >> 3, bn = inner & 7;
  const int m0 = bm << 7, n0 = bn << 7;
  const u16* A = (seg == 0) ? XQ : (seg == 1) ? XK : XV;
  const u16* W = Wb + (long)seg * 1048576;
  const int wm = (w >> 1) << 6, wn = (w & 1) << 6;
  const int r0 = t >> 2, cc0 = (t & 3) * 8;
  const u16* gA0 = A + (long)(m0 + r0) * 1024 + cc0;
  const u16* gA1 = gA0 + 64 * 1024;
  const u16* gB0 = W + (long)(n0 + r0) * 1024 + cc0;
  const u16* gB1 = gB0 + 64 * 1024;

  async16(gA0, &As[0][t * 8]); async16(gA1, &As[0][(t + 256) * 8]);
  async16(gB0, &Bs[0][t * 8]); async16(gB1, &Bs[0][(t + 256) * 8]);

  f32x4 acc[4][4] = {};
  for (int k0 = 0; k0 < 1024; k0 += 32) {
    const int cur = (k0 >> 5) & 1;
    __syncthreads();
    if (k0 + 32 < 1024) {
      const int kn = k0 + 32, nb = cur ^ 1;
      async16(gA0 + kn, &As[nb][t * 8]); async16(gA1 + kn, &As[nb][(t + 256) * 8]);
      async16(gB0 + kn, &Bs[nb][t * 8]); async16(gB1 + kn, &Bs[nb][(t + 256) * 8]);
    }
    bf16x8 af[4], bfm[4];
#pragma unroll
    for (int i = 0; i < 4; i++)
      af[i] = *(const bf16x8*)&As[cur][(wm + i * 16 + l15) * 32 + quad * 8];
#pragma unroll
    for (int j = 0; j < 4; j++)
      bfm[j] = *(const bf16x8*)&Bs[cur][(wn + j * 16 + l15) * 32 + quad * 8];
#pragma unroll
    for (int i = 0; i < 4; i++)
#pragma unroll
      for (int j = 0; j < 4; j++)
        acc[i][j] = __builtin_amdgcn_mfma_f32_16x16x32_bf16(af[i], bfm[j], acc[i][j], 0, 0, 0);
  }

  if (seg == 2) {  // V: bias + transposed write V^T[(b*1024+col)*2048 + n]
#pragma unroll
    for (int i = 0; i < 4; i++) {
      int token = m0 + wm + i * 16 + quad * 4;
      int bb_ = token >> 11, n = token & 2047;
#pragma unroll
      for (int j = 0; j < 4; j++) {
        int col = n0 + wn + j * 16 + l15;
        float bb = bv[col];
        union { u16 us[4]; uint2 u2; } pk;
#pragma unroll
        for (int r = 0; r < 4; r++) pk.us[r] = bf16_rne(acc[i][j][r] + bb);
        *(uint2*)&VTB[(long)(bb_ * 1024 + col) * 2048 + n] = pk.u2;
      }
    }
  } else {
    const float* bias = seg ? bkb : bq;
    u16* C = seg ? KB : QB;
#pragma unroll
    for (int j = 0; j < 4; j++) {
      int col = n0 + wn + j * 16 + l15;
      float bb = bias[col];
      float scl = 1.f;
      if (seg == 0) {
        float g = gate[col >> 6];
        float sig = 1.f / (1.f + __builtin_amdgcn_exp2f(-g * 1.44269504f));
        scl = sig * 0.125f * 1.44269504f;
      }
#pragma unroll
      for (int i = 0; i < 4; i++) {
        int row = m0 + wm + i * 16 + quad * 4;
#pragma unroll
        for (int r = 0; r < 4; r++)
          C[(long)(row + r) * 1024 + col] = bf16_rne((acc[i][j][r] + bb) * scl);
      }
    }
  }
}

// ---------------- out-proj GEMM: 64x128 tiles, dbuf, fp32 out ----------------
__global__ __launch_bounds__(256, 2) void gemm_out(
    const u16* __restrict__ A, const u16* __restrict__ W,
    const float* __restrict__ bias, float* __restrict__ Cf) {
  __shared__ __attribute__((aligned(16))) u16 As[2][64 * 32];
  __shared__ __attribute__((aligned(16))) u16 Bs[2][128 * 32];
  const int t = threadIdx.x, lane = t & 63, w = t >> 6;
  const int l15 = lane & 15, quad = lane >> 4;
  const int bm = blockIdx.x >> 3, bn = blockIdx.x & 7;
  const int m0 = bm << 6, n0 = bn << 7;
  const int wm = (w >> 1) << 5, wn = (w & 1) << 6;
  const int r0 = t >> 2, cc0 = (t & 3) * 8;
  const u16* gA = A + (long)(m0 + r0) * 1024 + cc0;
  const u16* gB0 = W + (long)(n0 + r0) * 1024 + cc0;
  const u16* gB1 = gB0 + 64 * 1024;

  async16(gA, &As[0][t * 8]);
  async16(gB0, &Bs[0][t * 8]); async16(gB1, &Bs[0][(t + 256) * 8]);

  f32x4 acc[2][4] = {};
  for (int k0 = 0; k0 < 1024; k0 += 32) {
    const int cur = (k0 >> 5) & 1;
    __syncthreads();
    if (k0 + 32 < 1024) {
      const int kn = k0 + 32, nb = cur ^ 1;
      async16(gA + kn, &As[nb][t * 8]);
      async16(gB0 + kn, &Bs[nb][t * 8]); async16(gB1 + kn, &Bs[nb][(t + 256) * 8]);
    }
    bf16x8 af[2], bfm[4];
#pragma unroll
    for (int i = 0; i < 2; i++)
      af[i] = *(const bf16x8*)&As[cur][(wm + i * 16 + l15) * 32 + quad * 8];
#pragma unroll
    for (int j = 0; j < 4; j++)
      bfm[j] = *(const bf16x8*)&Bs[cur][(wn + j * 16 + l15) * 32 + quad * 8];
#pragma unroll
    for (int i = 0; i < 2; i++)
#pragma unroll
      for (int j = 0; j < 4; j++)
        acc[i][j] = __builtin_amdgcn_mfma_f32_16x16x32_bf16(af[i], bfm[j], acc[i][j], 0, 0, 0);
  }

#pragma unroll
  for (int j = 0; j < 4; j++) {
    int col = n0 + wn + j * 16 + l15;
    float bb = bias[col];
#pragma unroll
    for (int i = 0; i < 2; i++) {
      int row = m0 + wm + i * 16 + quad * 4;
#pragma unroll
      for (int r = 0; r < 4; r++)
        Cf[(long)(row + r) * 1024 + col] = acc[i][j][r] + bb;
    }
  }
}

// ---------------- flash attention: 2 waves/block, 64 q-rows/wave ----------------
// grid (16,16,2) x 128 thr. No-max softmax (Q pre-scaled to exp2 domain).
// Per-wave Ps (no barrier for P roundtrip); shared K/V dbuf (1 barrier/kt).
__global__ __launch_bounds__(128) void attn_kernel(
    const u16* __restrict__ Q, const u16* __restrict__ Kb,
    const u16* __restrict__ Vt, u16* __restrict__ AO) {
  __shared__ __attribute__((aligned(16))) u16 Ks[2][64 * 64];
  __shared__ __attribute__((aligned(16))) u16 Vs[2][64 * 64];
  __shared__ __attribute__((aligned(16))) u16 Ps[2][64 * 64];
  const int t = threadIdx.x, lane = t & 63, w = t >> 6;
  const int l15 = lane & 15, quad = lane >> 4;
  const int qt = blockIdx.x, h = blockIdx.y, b = blockIdx.z;
  const int q0 = qt * 128, tok0 = b * 2048;
  const u16* Kbase = Kb + (long)tok0 * 1024 + h * 64;
  const u16* Vbase = Vt + (long)(b * 1024 + h * 64) * 2048;

  // loop-invariant Q fragments (rows w*64 .. w*64+63)
  bf16x8 aq[4][2];
#pragma unroll
  for (int mi = 0; mi < 4; mi++) {
    long row = tok0 + q0 + w * 64 + mi * 16 + l15;
#pragma unroll
    for (int ks = 0; ks < 2; ks++)
      aq[mi][ks] = *(const bf16x8*)&Q[row * 1024 + h * 64 + ks * 32 + quad * 8];
  }

  // stage kt=0 (xor-swizzled 16B chunks, swizzle applied at global source)
#pragma unroll
  for (int i = 0; i < 4; i++) {
    int c = i * 128 + t, r = c >> 3, cc = c & 7, ccs = cc ^ (r & 7);
    async16(&Kbase[(long)r * 1024 + ccs * 8], &Ks[0][c * 8]);
    async16(&Vbase[(long)r * 2048 + ccs * 8], &Vs[0][c * 8]);
  }

  float l_st[4][4] = {};
  f32x4 O[4][4] = {};

  for (int kt = 0; kt < 32; kt++) {
    const int cur = kt & 1;
    __syncthreads();
    if (kt + 1 < 32) {
      const int k0n = (kt + 1) * 64, nb = cur ^ 1;
#pragma unroll
      for (int i = 0; i < 4; i++) {
        int c = i * 128 + t, r = c >> 3, cc = c & 7, ccs = cc ^ (r & 7);
        async16(&Kbase[(long)(k0n + r) * 1024 + ccs * 8], &Ks[nb][c * 8]);
        async16(&Vbase[(long)r * 2048 + k0n + ccs * 8], &Vs[nb][c * 8]);
      }
    }

    // S = Q K^T : 4 q-mtiles x 4 key-ntiles
    f32x4 s[4][4] = {};
#pragma unroll
    for (int ks = 0; ks < 2; ks++) {
      bf16x8 bk_[4];
#pragma unroll
      for (int j = 0; j < 4; j++) {
        int rl = j * 16 + l15;
        bk_[j] = *(const bf16x8*)&Ks[cur][rl * 64 + ((ks * 4 + quad) ^ (rl & 7)) * 8];
      }
#pragma unroll
      for (int mi = 0; mi < 4; mi++)
#pragma unroll
        for (int j = 0; j < 4; j++)
          s[mi][j] = __builtin_amdgcn_mfma_f32_16x16x32_bf16(aq[mi][ks], bk_[j], s[mi][j], 0, 0, 0);
    }

    // exp2 + deferred l + P -> per-wave LDS (swizzled)
#pragma unroll
    for (int mi = 0; mi < 4; mi++) {
#pragma unroll
      for (int r = 0; r < 4; r++) {
        float p0 = __builtin_amdgcn_exp2f(s[mi][0][r]);
        float p1 = __builtin_amdgcn_exp2f(s[mi][1][r]);
        float p2 = __builtin_amdgcn_exp2f(s[mi][2][r]);
        float p3 = __builtin_amdgcn_exp2f(s[mi][3][r]);
        l_st[mi][r] += (p0 + p1) + (p2 + p3);
        const int prow = mi * 16 + quad * 4 + r, sw = prow & 7;
        u16* pr = &Ps[w][prow * 64];
        const int hi = l15 >> 3, e0 = l15 & 7;
        pr[((0 + hi) ^ sw) * 8 + e0] = cvt16(p0);
        pr[((2 + hi) ^ sw) * 8 + e0] = cvt16(p1);
        pr[((4 + hi) ^ sw) * 8 + e0] = cvt16(p2);
        pr[((6 + hi) ^ sw) * 8 + e0] = cvt16(p3);
      }
    }

    // O += P @ V
#pragma unroll
    for (int ks = 0; ks < 2; ks++) {
      bf16x8 ap[4], bv_[4];
#pragma unroll
      for (int mi = 0; mi < 4; mi++) {
        int rl = mi * 16 + l15;
        ap[mi] = *(const bf16x8*)&Ps[w][rl * 64 + ((ks * 4 + quad) ^ (rl & 7)) * 8];
      }
#pragma unroll
      for (int dj = 0; dj < 4; dj++) {
        int rl = dj * 16 + l15;
        bv_[dj] = *(const bf16x8*)&Vs[cur][rl * 64 + ((ks * 4 + quad) ^ (rl & 7)) * 8];
      }
#pragma unroll
      for (int mi = 0; mi < 4; mi++)
#pragma unroll
        for (int dj = 0; dj < 4; dj++)
          O[mi][dj] = __builtin_amdgcn_mfma_f32_16x16x32_bf16(ap[mi], bv_[dj], O[mi][dj], 0, 0, 0);
    }
  }

  // epilogue: reduce l over the 16 lanes sharing each row, scale, store
#pragma unroll
  for (int mi = 0; mi < 4; mi++) {
#pragma unroll
    for (int r = 0; r < 4; r++) {
      float ls = l_st[mi][r];
      ls += __shfl_xor(ls, 1); ls += __shfl_xor(ls, 2);
      ls += __shfl_xor(ls, 4); ls += __shfl_xor(ls, 8);
      float inv = 1.f / ls;
      long row = tok0 + q0 + w * 64 + mi * 16 + quad * 4 + r;
#pragma unroll
      for (int dj = 0; dj < 4; dj++)
        AO[row * 1024 + h * 64 + dj * 16 + l15] = cvt16(O[mi][dj][r] * inv);
    }
  }
}

extern "C" void kernel_launch(void* const* d_in, const int* in_sizes, int n_in,
                              void* d_out, int out_size, void* d_ws, size_t ws_size,
                              hipStream_t stream) {
  const float* q  = (const float*)d_in[0];
  const float* k  = (const float*)d_in[1];
  const float* v  = (const float*)d_in[2];
  const float* Wq = (const float*)d_in[3];
  const float* bq = (const float*)d_in[4];
  const float* Wk = (const float*)d_in[5];
  const float* bk = (const float*)d_in[6];
  const float* Wv = (const float*)d_in[7];
  const float* bv = (const float*)d_in[8];
  const float* Wo = (const float*)d_in[9];
  const float* bo = (const float*)d_in[10];
  const float* gate = (const float*)d_in[11];
  float* out = (float*)d_out;
  char* ws = (char*)d_ws;

  const size_t MB = 1u << 20;
  u16* WQB = (u16*)(ws + 0 * MB);   // WQ|WK|WV|WO contiguous (2MB each)
  u16* WKB = (u16*)(ws + 2 * MB);
  u16* WVB = (u16*)(ws + 4 * MB);
  u16* WOB = (u16*)(ws + 6 * MB);
  u16* XQ  = (u16*)(ws + 8 * MB);
  u16* XK  = (u16*)(ws + 16 * MB);
  u16* XV  = (u16*)(ws + 24 * MB);
  u16* QB  = (u16*)(ws + 32 * MB);
  u16* KB  = (u16*)(ws + 40 * MB);
  u16* AOB = (u16*)(ws + 8 * MB);   // over dead XQ
  u16* VTB = (u16*)d_out;           // d_out (16MB fp32) as scratch until final GEMM

  cast_all<<<8192, 256, 0, stream>>>(q, k, v, Wq, Wk, Wv, Wo,
                                     XQ, XK, XV, WQB, WKB, WVB, WOB);
  gemm_qkv<<<768, 256, 0, stream>>>(XQ, XK, XV, WQB, bq, bk, bv, gate, QB, KB, VTB);
  attn_kernel<<<dim3(16, 16, 2), 128, 0, stream>>>(QB, KB, VTB, AOB);
  gemm_out<<<512, 256, 0, stream>>>(AOB, WOB, bo, out);
}

// Round 4
// 243.743 us; speedup vs baseline: 1.0734x; 1.0734x over previous
//
#include <hip/hip_runtime.h>
#include <hip/hip_bf16.h>
#include <cstdint>

// GatedMultiheadAttention: B=2, N=2048, E=1024, H=16, D=64
// R4: attn -> BQ=64, 128-thr blocks (2 waves x 32 q-rows), 1024 blocks,
// LDS 40KB -> 4 blocks/CU = 8 waves/CU in 4 independent barrier groups.
// (R3's 512x2-wave grid capped at 4 waves/CU -> latency-bound regression.)
// ws (48MB): W 0-8 | XQ 8-16, XK 16-24, XV 24-32, QB 32-40, KB 40-48 |
// AOB = 8-16 (over dead XQ). VTB = d_out (dead until final GEMM).

#define DEV __device__ __forceinline__
typedef __attribute__((ext_vector_type(8))) short bf16x8;
typedef __attribute__((ext_vector_type(4))) float f32x4;
typedef unsigned short u16;

DEV void async16(const void* g, void* l) {
  __builtin_amdgcn_global_load_lds(
      (const __attribute__((address_space(1))) unsigned int*)g,
      (__attribute__((address_space(3))) unsigned int*)l, 16, 0, 0);
}

DEV u16 bf16_rne(float f) {
  unsigned int u = __builtin_bit_cast(unsigned int, f);
  u += 0x7FFFu + ((u >> 16) & 1u);
  return (u16)(u >> 16);
}

DEV u16 cvt16(float x) {
  __hip_bfloat16 h = __float2bfloat16(x);
  return __builtin_bit_cast(u16, h);
}

// ---------------- one fused cast: q,k,v + 4 weights ----------------
__global__ __launch_bounds__(256) void cast_all(
    const float* __restrict__ q, const float* __restrict__ k, const float* __restrict__ v,
    const float* __restrict__ Wq, const float* __restrict__ Wk,
    const float* __restrict__ Wv, const float* __restrict__ Wo,
    u16* __restrict__ XQ, u16* __restrict__ XK, u16* __restrict__ XV,
    u16* __restrict__ WQB, u16* __restrict__ WKB, u16* __restrict__ WVB,
    u16* __restrict__ WOB) {
  int idx = blockIdx.x * 256 + threadIdx.x;  // one 8-elem item each
  const float* src; u16* dst; int i;
  if      (idx <  524288) { src = q;  dst = XQ;  i = idx; }
  else if (idx < 1048576) { src = k;  dst = XK;  i = idx -  524288; }
  else if (idx < 1572864) { src = v;  dst = XV;  i = idx - 1048576; }
  else if (idx < 1703936) { src = Wq; dst = WQB; i = idx - 1572864; }
  else if (idx < 1835008) { src = Wk; dst = WKB; i = idx - 1703936; }
  else if (idx < 1966080) { src = Wv; dst = WVB; i = idx - 1835008; }
  else                    { src = Wo; dst = WOB; i = idx - 1966080; }
  const float4* p = (const float4*)src + (size_t)i * 2;
  float4 a = p[0], b = p[1];
  union { u16 us[8]; uint4 vv; } u;
  u.us[0] = bf16_rne(a.x); u.us[1] = bf16_rne(a.y);
  u.us[2] = bf16_rne(a.z); u.us[3] = bf16_rne(a.w);
  u.us[4] = bf16_rne(b.x); u.us[5] = bf16_rne(b.y);
  u.us[6] = bf16_rne(b.z); u.us[7] = bf16_rne(b.w);
  ((uint4*)dst)[i] = u.vv;
}

// ---------------- fused QKV projection GEMM (768 blocks, 128x128, dbuf) ------
// seg = bx>>8: 0=Q (gate-scale folded), 1=K, 2=V (writes V^T into d_out).
__global__ __launch_bounds__(256, 2) void gemm_qkv(
    const u16* __restrict__ XQ, const u16* __restrict__ XK, const u16* __restrict__ XV,
    const u16* __restrict__ Wb,  // WQ|WK|WV contiguous, 1M elems apart
    const float* __restrict__ bq, const float* __restrict__ bkb, const float* __restrict__ bv,
    const float* __restrict__ gate,
    u16* __restrict__ QB, u16* __restrict__ KB, u16* __restrict__ VTB) {
  __shared__ __attribute__((aligned(16))) u16 As[2][128 * 32];
  __shared__ __attribute__((aligned(16))) u16 Bs[2][128 * 32];
  const int t = threadIdx.x, lane = t & 63, w = t >> 6;
  const int l15 = lane & 15, quad = lane >> 4;
  const int seg = blockIdx.x >> 8, inner = blockIdx.x & 255;
  const int bm = inner >> 3, bn = inner & 7;
  const int m0 = bm << 7, n0 = bn << 7;
  const u16* A = (seg == 0) ? XQ : (seg == 1) ? XK : XV;
  const u16* W = Wb + (long)seg * 1048576;
  const int wm = (w >> 1) << 6, wn = (w & 1) << 6;
  const int r0 = t >> 2, cc0 = (t & 3) * 8;
  const u16* gA0 = A + (long)(m0 + r0) * 1024 + cc0;
  const u16* gA1 = gA0 + 64 * 1024;
  const u16* gB0 = W + (long)(n0 + r0) * 1024 + cc0;
  const u16* gB1 = gB0 + 64 * 1024;

  async16(gA0, &As[0][t * 8]); async16(gA1, &As[0][(t + 256) * 8]);
  async16(gB0, &Bs[0][t * 8]); async16(gB1, &Bs[0][(t + 256) * 8]);

  f32x4 acc[4][4] = {};
  for (int k0 = 0; k0 < 1024; k0 += 32) {
    const int cur = (k0 >> 5) & 1;
    __syncthreads();
    if (k0 + 32 < 1024) {
      const int kn = k0 + 32, nb = cur ^ 1;
      async16(gA0 + kn, &As[nb][t * 8]); async16(gA1 + kn, &As[nb][(t + 256) * 8]);
      async16(gB0 + kn, &Bs[nb][t * 8]); async16(gB1 + kn, &Bs[nb][(t + 256) * 8]);
    }
    bf16x8 af[4], bfm[4];
#pragma unroll
    for (int i = 0; i < 4; i++)
      af[i] = *(const bf16x8*)&As[cur][(wm + i * 16 + l15) * 32 + quad * 8];
#pragma unroll
    for (int j = 0; j < 4; j++)
      bfm[j] = *(const bf16x8*)&Bs[cur][(wn + j * 16 + l15) * 32 + quad * 8];
#pragma unroll
    for (int i = 0; i < 4; i++)
#pragma unroll
      for (int j = 0; j < 4; j++)
        acc[i][j] = __builtin_amdgcn_mfma_f32_16x16x32_bf16(af[i], bfm[j], acc[i][j], 0, 0, 0);
  }

  if (seg == 2) {  // V: bias + transposed write V^T[(b*1024+col)*2048 + n]
#pragma unroll
    for (int i = 0; i < 4; i++) {
      int token = m0 + wm + i * 16 + quad * 4;
      int bb_ = token >> 11, n = token & 2047;
#pragma unroll
      for (int j = 0; j < 4; j++) {
        int col = n0 + wn + j * 16 + l15;
        float bb = bv[col];
        union { u16 us[4]; uint2 u2; } pk;
#pragma unroll
        for (int r = 0; r < 4; r++) pk.us[r] = bf16_rne(acc[i][j][r] + bb);
        *(uint2*)&VTB[(long)(bb_ * 1024 + col) * 2048 + n] = pk.u2;
      }
    }
  } else {
    const float* bias = seg ? bkb : bq;
    u16* C = seg ? KB : QB;
#pragma unroll
    for (int j = 0; j < 4; j++) {
      int col = n0 + wn + j * 16 + l15;
      float bb = bias[col];
      float scl = 1.f;
      if (seg == 0) {
        float g = gate[col >> 6];
        float sig = 1.f / (1.f + __builtin_amdgcn_exp2f(-g * 1.44269504f));
        scl = sig * 0.125f * 1.44269504f;
      }
#pragma unroll
      for (int i = 0; i < 4; i++) {
        int row = m0 + wm + i * 16 + quad * 4;
#pragma unroll
        for (int r = 0; r < 4; r++)
          C[(long)(row + r) * 1024 + col] = bf16_rne((acc[i][j][r] + bb) * scl);
      }
    }
  }
}

// ---------------- out-proj GEMM: 64x128 tiles, dbuf, fp32 out ----------------
__global__ __launch_bounds__(256, 2) void gemm_out(
    const u16* __restrict__ A, const u16* __restrict__ W,
    const float* __restrict__ bias, float* __restrict__ Cf) {
  __shared__ __attribute__((aligned(16))) u16 As[2][64 * 32];
  __shared__ __attribute__((aligned(16))) u16 Bs[2][128 * 32];
  const int t = threadIdx.x, lane = t & 63, w = t >> 6;
  const int l15 = lane & 15, quad = lane >> 4;
  const int bm = blockIdx.x >> 3, bn = blockIdx.x & 7;
  const int m0 = bm << 6, n0 = bn << 7;
  const int wm = (w >> 1) << 5, wn = (w & 1) << 6;
  const int r0 = t >> 2, cc0 = (t & 3) * 8;
  const u16* gA = A + (long)(m0 + r0) * 1024 + cc0;
  const u16* gB0 = W + (long)(n0 + r0) * 1024 + cc0;
  const u16* gB1 = gB0 + 64 * 1024;

  async16(gA, &As[0][t * 8]);
  async16(gB0, &Bs[0][t * 8]); async16(gB1, &Bs[0][(t + 256) * 8]);

  f32x4 acc[2][4] = {};
  for (int k0 = 0; k0 < 1024; k0 += 32) {
    const int cur = (k0 >> 5) & 1;
    __syncthreads();
    if (k0 + 32 < 1024) {
      const int kn = k0 + 32, nb = cur ^ 1;
      async16(gA + kn, &As[nb][t * 8]);
      async16(gB0 + kn, &Bs[nb][t * 8]); async16(gB1 + kn, &Bs[nb][(t + 256) * 8]);
    }
    bf16x8 af[2], bfm[4];
#pragma unroll
    for (int i = 0; i < 2; i++)
      af[i] = *(const bf16x8*)&As[cur][(wm + i * 16 + l15) * 32 + quad * 8];
#pragma unroll
    for (int j = 0; j < 4; j++)
      bfm[j] = *(const bf16x8*)&Bs[cur][(wn + j * 16 + l15) * 32 + quad * 8];
#pragma unroll
    for (int i = 0; i < 2; i++)
#pragma unroll
      for (int j = 0; j < 4; j++)
        acc[i][j] = __builtin_amdgcn_mfma_f32_16x16x32_bf16(af[i], bfm[j], acc[i][j], 0, 0, 0);
  }

#pragma unroll
  for (int j = 0; j < 4; j++) {
    int col = n0 + wn + j * 16 + l15;
    float bb = bias[col];
#pragma unroll
    for (int i = 0; i < 2; i++) {
      int row = m0 + wm + i * 16 + quad * 4;
#pragma unroll
      for (int r = 0; r < 4; r++)
        Cf[(long)(row + r) * 1024 + col] = acc[i][j][r] + bb;
    }
  }
}

// ---------------- flash attention: BQ=64, 2 waves x 32 q-rows ----------------
// grid (32,16,2) x 128 thr = 2048 waves = 8/CU (4 blocks/CU via 40KB LDS).
// No-max softmax (Q pre-scaled to exp2 domain); per-wave Ps; shared K/V dbuf.
__global__ __launch_bounds__(128, 2) void attn_kernel(
    const u16* __restrict__ Q, const u16* __restrict__ Kb,
    const u16* __restrict__ Vt, u16* __restrict__ AO) {
  __shared__ __attribute__((aligned(16))) u16 Ks[2][64 * 64];
  __shared__ __attribute__((aligned(16))) u16 Vs[2][64 * 64];
  __shared__ __attribute__((aligned(16))) u16 Ps[2][32 * 64];
  const int t = threadIdx.x, lane = t & 63, w = t >> 6;
  const int l15 = lane & 15, quad = lane >> 4;
  const int qt = blockIdx.x, h = blockIdx.y, b = blockIdx.z;
  const int q0 = qt * 64, tok0 = b * 2048;
  const u16* Kbase = Kb + (long)tok0 * 1024 + h * 64;
  const u16* Vbase = Vt + (long)(b * 1024 + h * 64) * 2048;

  // loop-invariant Q fragments (wave rows q0 + w*32 .. +31)
  bf16x8 aq[2][2];
#pragma unroll
  for (int i = 0; i < 2; i++) {
    long row = tok0 + q0 + w * 32 + i * 16 + l15;
#pragma unroll
    for (int ks = 0; ks < 2; ks++)
      aq[i][ks] = *(const bf16x8*)&Q[row * 1024 + h * 64 + ks * 32 + quad * 8];
  }

  // stage kt=0 (xor-swizzled 16B chunks, swizzle applied at global source)
#pragma unroll
  for (int i = 0; i < 4; i++) {
    int c = i * 128 + t, r = c >> 3, cc = c & 7, ccs = cc ^ (r & 7);
    async16(&Kbase[(long)r * 1024 + ccs * 8], &Ks[0][c * 8]);
    async16(&Vbase[(long)r * 2048 + ccs * 8], &Vs[0][c * 8]);
  }

  float l_st[2][4] = {};
  f32x4 O[2][4] = {};

  for (int kt = 0; kt < 32; kt++) {
    const int cur = kt & 1;
    __syncthreads();
    if (kt + 1 < 32) {
      const int k0n = (kt + 1) * 64, nb = cur ^ 1;
#pragma unroll
      for (int i = 0; i < 4; i++) {
        int c = i * 128 + t, r = c >> 3, cc = c & 7, ccs = cc ^ (r & 7);
        async16(&Kbase[(long)(k0n + r) * 1024 + ccs * 8], &Ks[nb][c * 8]);
        async16(&Vbase[(long)r * 2048 + k0n + ccs * 8], &Vs[nb][c * 8]);
      }
    }

    // S = Q K^T (already in exp2 domain)
    f32x4 s[2][4] = {};
#pragma unroll
    for (int ks = 0; ks < 2; ks++) {
      bf16x8 bk_[4];
#pragma unroll
      for (int j = 0; j < 4; j++) {
        int rl = j * 16 + l15;
        bk_[j] = *(const bf16x8*)&Ks[cur][rl * 64 + ((ks * 4 + quad) ^ (rl & 7)) * 8];
      }
#pragma unroll
      for (int i = 0; i < 2; i++)
#pragma unroll
        for (int j = 0; j < 4; j++)
          s[i][j] = __builtin_amdgcn_mfma_f32_16x16x32_bf16(aq[i][ks], bk_[j], s[i][j], 0, 0, 0);
    }

    // exp2 + deferred l + P -> per-wave LDS (swizzled)
#pragma unroll
    for (int i = 0; i < 2; i++) {
#pragma unroll
      for (int r = 0; r < 4; r++) {
        float p0 = __builtin_amdgcn_exp2f(s[i][0][r]);
        float p1 = __builtin_amdgcn_exp2f(s[i][1][r]);
        float p2 = __builtin_amdgcn_exp2f(s[i][2][r]);
        float p3 = __builtin_amdgcn_exp2f(s[i][3][r]);
        l_st[i][r] += (p0 + p1) + (p2 + p3);
        const int prow = i * 16 + quad * 4 + r, sw = prow & 7;
        u16* pr = &Ps[w][prow * 64];
        const int hi = l15 >> 3, e0 = l15 & 7;
        pr[((0 + hi) ^ sw) * 8 + e0] = cvt16(p0);
        pr[((2 + hi) ^ sw) * 8 + e0] = cvt16(p1);
        pr[((4 + hi) ^ sw) * 8 + e0] = cvt16(p2);
        pr[((6 + hi) ^ sw) * 8 + e0] = cvt16(p3);
      }
    }

    // O += P @ V
#pragma unroll
    for (int ks = 0; ks < 2; ks++) {
      bf16x8 ap[2], bv_[4];
#pragma unroll
      for (int i = 0; i < 2; i++) {
        int rl = i * 16 + l15;
        ap[i] = *(const bf16x8*)&Ps[w][rl * 64 + ((ks * 4 + quad) ^ (rl & 7)) * 8];
      }
#pragma unroll
      for (int dj = 0; dj < 4; dj++) {
        int rl = dj * 16 + l15;
        bv_[dj] = *(const bf16x8*)&Vs[cur][rl * 64 + ((ks * 4 + quad) ^ (rl & 7)) * 8];
      }
#pragma unroll
      for (int i = 0; i < 2; i++)
#pragma unroll
        for (int dj = 0; dj < 4; dj++)
          O[i][dj] = __builtin_amdgcn_mfma_f32_16x16x32_bf16(ap[i], bv_[dj], O[i][dj], 0, 0, 0);
    }
  }

  // epilogue: reduce l over the 16 lanes sharing each row, scale, store
#pragma unroll
  for (int i = 0; i < 2; i++) {
#pragma unroll
    for (int r = 0; r < 4; r++) {
      float ls = l_st[i][r];
      ls += __shfl_xor(ls, 1); ls += __shfl_xor(ls, 2);
      ls += __shfl_xor(ls, 4); ls += __shfl_xor(ls, 8);
      float inv = 1.f / ls;
      long row = tok0 + q0 + w * 32 + i * 16 + quad * 4 + r;
#pragma unroll
      for (int dj = 0; dj < 4; dj++)
        AO[row * 1024 + h * 64 + dj * 16 + l15] = cvt16(O[i][dj][r] * inv);
    }
  }
}

extern "C" void kernel_launch(void* const* d_in, const int* in_sizes, int n_in,
                              void* d_out, int out_size, void* d_ws, size_t ws_size,
                              hipStream_t stream) {
  const float* q  = (const float*)d_in[0];
  const float* k  = (const float*)d_in[1];
  const float* v  = (const float*)d_in[2];
  const float* Wq = (const float*)d_in[3];
  const float* bq = (const float*)d_in[4];
  const float* Wk = (const float*)d_in[5];
  const float* bk = (const float*)d_in[6];
  const float* Wv = (const float*)d_in[7];
  const float* bv = (const float*)d_in[8];
  const float* Wo = (const float*)d_in[9];
  const float* bo = (const float*)d_in[10];
  const float* gate = (const float*)d_in[11];
  float* out = (float*)d_out;
  char* ws = (char*)d_ws;

  const size_t MB = 1u << 20;
  u16* WQB = (u16*)(ws + 0 * MB);   // WQ|WK|WV|WO contiguous (2MB each)
  u16* WKB = (u16*)(ws + 2 * MB);
  u16* WVB = (u16*)(ws + 4 * MB);
  u16* WOB = (u16*)(ws + 6 * MB);
  u16* XQ  = (u16*)(ws + 8 * MB);
  u16* XK  = (u16*)(ws + 16 * MB);
  u16* XV  = (u16*)(ws + 24 * MB);
  u16* QB  = (u16*)(ws + 32 * MB);
  u16* KB  = (u16*)(ws + 40 * MB);
  u16* AOB = (u16*)(ws + 8 * MB);   // over dead XQ
  u16* VTB = (u16*)d_out;           // d_out (16MB fp32) as scratch until final GEMM

  cast_all<<<8192, 256, 0, stream>>>(q, k, v, Wq, Wk, Wv, Wo,
                                     XQ, XK, XV, WQB, WKB, WVB, WOB);
  gemm_qkv<<<768, 256, 0, stream>>>(XQ, XK, XV, WQB, bq, bk, bv, gate, QB, KB, VTB);
  attn_kernel<<<dim3(32, 16, 2), 128, 0, stream>>>(QB, KB, VTB, AOB);
  gemm_out<<<512, 256, 0, stream>>>(AOB, WOB, bo, out);
}